// Round 7
// baseline (649.666 us; speedup 1.0000x reference)
//
#include <hip/hip_runtime.h>

typedef unsigned short u16;
typedef unsigned int u32;
typedef short bf16x8 __attribute__((ext_vector_type(8)));
typedef float f32x4 __attribute__((ext_vector_type(4)));

// ---------- bf16 helpers ----------
__device__ __forceinline__ float b2f(u16 v) { return __uint_as_float(((u32)v) << 16); }
__device__ __forceinline__ u16 f2b(float f) {   // round-to-nearest-even
    u32 x = __float_as_uint(f);
    return (u16)((x + 0x7fffu + ((x >> 16) & 1u)) >> 16);
}
__device__ __forceinline__ float lo16(u32 w) { return __uint_as_float(w << 16); }
__device__ __forceinline__ float hi16(u32 w) { return __uint_as_float(w & 0xffff0000u); }

#define S_LEN 256
#define B_SZ  512
#define DM    128
#define DFF   512
#define MROWS (S_LEN * B_SZ)   // 131072

// swizzled LDS address for a [row][128] bf16 tile, 16 slots of 8
__device__ __forceinline__ int sw16(int r, int d) {
    return r * 128 + ((((d >> 3) ^ (r & 15)) & 15) << 3) + (d & 7);
}

// ================= dtype detect =================
__global__ __launch_bounds__(256) void detect_kernel(const u32* __restrict__ embw,
                                                     int* __restrict__ flag) {
    int z = 0, big = 0;
    for (int i = threadIdx.x; i < 8192; i += 256) {
        u32 w = embw[i];
        u32 lo = w & 0xffffu;
        if (lo == 0u) z++;
        else if (((lo >> 7) & 0xffu) >= 0xC0u) big++;
    }
#pragma unroll
    for (int off = 32; off > 0; off >>= 1) {
        z   += __shfl_xor(z, off, 64);
        big += __shfl_xor(big, off, 64);
    }
    __shared__ int zz[4], bb[4];
    if ((threadIdx.x & 63) == 0) { zz[threadIdx.x >> 6] = z; bb[threadIdx.x >> 6] = big; }
    __syncthreads();
    if (threadIdx.x == 0) {
        int Z = zz[0] + zz[1] + zz[2] + zz[3];
        int Bc = bb[0] + bb[1] + bb[2] + bb[3];
        flag[0] = (Z > 4096 || Bc > 16) ? 1 : 0;   // 1 = fp32 storage
    }
}

// ================= convert all float inputs -> canonical bf16 =================
struct Ptrs { const void* p[17]; };

__global__ __launch_bounds__(256) void convert_kernel(Ptrs ps, u16* __restrict__ canon,
                                                      const int* __restrict__ flag) {
    const int cnt[17] = {16384,32768,256,32768,256,32768,256,131072,1024,131072,
                         256,256,256,256,256,1280,10};
    const int off[17] = {0,16384,49152,49408,82176,82432,115200,115456,246528,
                         247552,378624,378880,379136,379392,379648,379904,381184};
    const int bst[18] = {0,8,24,25,41,42,58,59,123,124,188,189,190,191,192,193,194,195};
    const int isf = *flag;
    const int blk = blockIdx.x;
    int idx = 0;
#pragma unroll
    for (int i = 0; i < 17; ++i) if (blk >= bst[i + 1]) idx = i + 1;
    const int local = blk - bst[idx];
    const int n = cnt[idx];
    const void* sp = ps.p[idx];
    u16* dp = canon + off[idx];
#pragma unroll
    for (int j = 0; j < 8; ++j) {
        int e = local * 2048 + j * 256 + threadIdx.x;
        if (e < n) {
            u16 v = isf ? f2b(((const float*)sp)[e]) : ((const u16*)sp)[e];
            dp[e] = v;
        }
    }
}

// ================= embed + positional encoding → X bf16 =================
__global__ __launch_bounds__(256) void embed_kernel(const int* __restrict__ src,
                                                    const u16* __restrict__ emb,
                                                    u16* __restrict__ X) {
    int idx = blockIdx.x * 256 + threadIdx.x;      // one per bf16 pair
    int d2 = idx & 63;
    int m = idx >> 6;              // s*512 + b
    int s = m >> 9;
    int b = m & 511;
    int tok = src[b * S_LEN + s];
    int d = d2 * 2;
    float e0 = b2f(emb[tok * DM + d])     * 11.3137084989847604f; // sqrt(128)
    float e1 = b2f(emb[tok * DM + d + 1]) * 11.3137084989847604f;
    float ang = (float)s * expf((float)d * -0.0719557841560639f); // -ln(10000)/128
    float v0 = e0 + sinf(ang);
    float v1 = e1 + cosf(ang);
    u32 w = (u32)f2b(v0) | ((u32)f2b(v1) << 16);
    *(u32*)(X + (size_t)m * DM + d) = w;
}

// ================= kvproj (MFMA): per-s K/V proj + KV^T + Ksum =================
// v3: X A-frags loaded once per chunk direct global→VGPR (no Xs LDS/staging
// barriers). Weights VGPR-resident. LDS only for Kt/Vt transpose (32KB).
__global__ __launch_bounds__(256) void kvproj_kernel(
    const u16* __restrict__ X, const u16* __restrict__ Wk, const u16* __restrict__ bk,
    const u16* __restrict__ Wv, const u16* __restrict__ bv,
    u16* __restrict__ KVt, float* __restrict__ Ksum)
{
    __shared__ __align__(16) char sm_[32768];
    u16* Kt = (u16*)sm_;             // 16KB: 128 e x 64 b, 8-slot swizzle
    u16* Vt = (u16*)(sm_ + 16384);   // 16KB: 128 e x 64 b
    const int s = blockIdx.x, t = threadIdx.x;
    const int w = t >> 6, quad = (t >> 4) & 3, lr = t & 15;
    const u16* Xg = X + (size_t)s * B_SZ * DM;

    bf16x8 wkf[2][4], wvf[2][4];
    float kb[2], vb[2];
#pragma unroll
    for (int ct = 0; ct < 2; ++ct) {
        int e = w * 32 + ct * 16 + lr;
#pragma unroll
        for (int kc = 0; kc < 4; ++kc) {
            wkf[ct][kc] = *(const bf16x8*)(Wk + e * 128 + kc * 32 + quad * 8);
            wvf[ct][kc] = *(const bf16x8*)(Wv + e * 128 + kc * 32 + quad * 8);
        }
        kb[ct] = b2f(bk[e]);
        vb[ct] = b2f(bv[e]);
    }

    const f32x4 z4 = {0.f, 0.f, 0.f, 0.f};
    f32x4 kvacc[2][8];
#pragma unroll
    for (int dt = 0; dt < 2; ++dt)
#pragma unroll
        for (int ct = 0; ct < 8; ++ct) kvacc[dt][ct] = z4;
    float ks[2] = {0.f, 0.f};

#pragma unroll 1
    for (int b0 = 0; b0 < B_SZ; b0 += 64) {
        // X A-frags direct from global (identical across waves → L1-served)
        bf16x8 a[4][4];
#pragma unroll
        for (int mt = 0; mt < 4; ++mt)
#pragma unroll
            for (int kc = 0; kc < 4; ++kc)
                a[mt][kc] = *(const bf16x8*)(Xg + (size_t)(b0 + mt * 16 + lr) * DM
                                               + kc * 32 + quad * 8);
        // ---- K projection ----
        f32x4 pa[4][2];
#pragma unroll
        for (int mt = 0; mt < 4; ++mt) { pa[mt][0] = z4; pa[mt][1] = z4; }
#pragma unroll
        for (int kc = 0; kc < 4; ++kc)
#pragma unroll
            for (int ct = 0; ct < 2; ++ct)
#pragma unroll
                for (int mt = 0; mt < 4; ++mt)
                    pa[mt][ct] = __builtin_amdgcn_mfma_f32_16x16x32_bf16(a[mt][kc], wkf[ct][kc], pa[mt][ct], 0, 0, 0);
#pragma unroll
        for (int ct = 0; ct < 2; ++ct) {
            int e = w * 32 + ct * 16 + lr, e7 = e & 7;
#pragma unroll
            for (int mt = 0; mt < 4; ++mt) {
                u16 h[4]; float ssum = 0.f;
#pragma unroll
                for (int j = 0; j < 4; ++j) {
                    float v = fmaxf(pa[mt][ct][j] + kb[ct], 0.f) + 1e-6f;
                    h[j] = f2b(v); ssum += b2f(h[j]);
                }
                ks[ct] += ssum;
                uint2 pk; pk.x = (u32)h[0] | ((u32)h[1] << 16); pk.y = (u32)h[2] | ((u32)h[3] << 16);
                int bs = mt * 2 + (quad >> 1);
                *(uint2*)(Kt + e * 64 + (((bs ^ e7) & 7) << 3) + (quad & 1) * 4) = pk;
            }
        }
        // ---- V projection (reuse a frags) ----
#pragma unroll
        for (int mt = 0; mt < 4; ++mt) { pa[mt][0] = z4; pa[mt][1] = z4; }
#pragma unroll
        for (int kc = 0; kc < 4; ++kc)
#pragma unroll
            for (int ct = 0; ct < 2; ++ct)
#pragma unroll
                for (int mt = 0; mt < 4; ++mt)
                    pa[mt][ct] = __builtin_amdgcn_mfma_f32_16x16x32_bf16(a[mt][kc], wvf[ct][kc], pa[mt][ct], 0, 0, 0);
#pragma unroll
        for (int ct = 0; ct < 2; ++ct) {
            int e = w * 32 + ct * 16 + lr, e7 = e & 7;
#pragma unroll
            for (int mt = 0; mt < 4; ++mt) {
                u16 h[4];
#pragma unroll
                for (int j = 0; j < 4; ++j) h[j] = f2b(pa[mt][ct][j] + vb[ct]);
                uint2 pk; pk.x = (u32)h[0] | ((u32)h[1] << 16); pk.y = (u32)h[2] | ((u32)h[3] << 16);
                int bs = mt * 2 + (quad >> 1);
                *(uint2*)(Vt + e * 64 + (((bs ^ e7) & 7) << 3) + (quad & 1) * 4) = pk;
            }
        }
        __syncthreads();   // Kt/Vt visible (Vt read cross-wave)
#pragma unroll
        for (int kc = 0; kc < 2; ++kc) {
            bf16x8 ka[2];
#pragma unroll
            for (int dt = 0; dt < 2; ++dt) {
                int d = (2 * w + dt) * 16 + lr;
                ka[dt] = *(const bf16x8*)(Kt + d * 64 + ((((kc * 4 + quad) ^ (d & 7)) & 7) << 3));
            }
#pragma unroll
            for (int ct = 0; ct < 8; ++ct) {
                int e = ct * 16 + lr;
                bf16x8 vf = *(const bf16x8*)(Vt + e * 64 + ((((kc * 4 + quad) ^ (e & 7)) & 7) << 3));
                kvacc[0][ct] = __builtin_amdgcn_mfma_f32_16x16x32_bf16(ka[0], vf, kvacc[0][ct], 0, 0, 0);
                kvacc[1][ct] = __builtin_amdgcn_mfma_f32_16x16x32_bf16(ka[1], vf, kvacc[1][ct], 0, 0, 0);
            }
        }
        __syncthreads();   // KV reads done before next iter overwrites Kt/Vt
    }
#pragma unroll
    for (int ct = 0; ct < 2; ++ct) {
        float v = ks[ct];
        v += __shfl_xor(v, 16, 64);
        v += __shfl_xor(v, 32, 64);
        if (quad == 0) Ksum[s * 128 + w * 32 + ct * 16 + lr] = v;
    }
    u16* KVg = KVt + (size_t)s * (DM * DM);
#pragma unroll
    for (int dt = 0; dt < 2; ++dt) {
        int d0 = (2 * w + dt) * 16 + quad * 4;
#pragma unroll
        for (int ct = 0; ct < 8; ++ct) {
            int e = ct * 16 + lr;
            u16 h[4];
#pragma unroll
            for (int j = 0; j < 4; ++j) h[j] = f2b(kvacc[dt][ct][j]);
            uint2 pk; pk.x = (u32)h[0] | ((u32)h[1] << 16); pk.y = (u32)h[2] | ((u32)h[3] << 16);
            *(uint2*)(KVg + e * 128 + d0) = pk;
        }
    }
}

// ================= attn (MFMA): Q-proj + Q·KV·Z + residual + LN =================
// v3: Wq/X/KVt fragments direct global→VGPR (wave-shared → L1). LDS only for
// the Qs C→A transpose (wave-private rows) → zero barriers.
__global__ __launch_bounds__(256) void attn_ln_kernel(
    const u16* X, const u16* __restrict__ Wq, const u16* __restrict__ bq,
    const u16* __restrict__ KVt, const float* __restrict__ Ksum,
    u16* Xout, const u16* __restrict__ g, const u16* __restrict__ beta)
{
    __shared__ __align__(16) u16 Qs[128 * 128];   // 32KB, sw16, wave-private rows
    const int blk = blockIdx.x, s = blk >> 2, rc = blk & 3, t = threadIdx.x;
    const int w = t >> 6, quad = (t >> 4) & 3, lr = t & 15;
    const size_t m0 = (size_t)s * B_SZ + rc * 128;

    const f32x4 z4 = {0.f, 0.f, 0.f, 0.f};
    f32x4 qacc[2][8];
#pragma unroll
    for (int mt = 0; mt < 2; ++mt)
#pragma unroll
        for (int ct = 0; ct < 8; ++ct) qacc[mt][ct] = z4;
#pragma unroll
    for (int kc = 0; kc < 4; ++kc) {
        bf16x8 a[2];
#pragma unroll
        for (int mt = 0; mt < 2; ++mt)
            a[mt] = *(const bf16x8*)(X + (m0 + w * 32 + mt * 16 + lr) * DM
                                       + kc * 32 + quad * 8);
#pragma unroll
        for (int ct = 0; ct < 8; ++ct) {
            bf16x8 wf = *(const bf16x8*)(Wq + (ct * 16 + lr) * DM + kc * 32 + quad * 8);
            qacc[0][ct] = __builtin_amdgcn_mfma_f32_16x16x32_bf16(a[0], wf, qacc[0][ct], 0, 0, 0);
            qacc[1][ct] = __builtin_amdgcn_mfma_f32_16x16x32_bf16(a[1], wf, qacc[1][ct], 0, 0, 0);
        }
    }
    // epilogue: relu+eps, Z partials (rounded Q), transpose-store Qs (wave-private)
    float ksm[8], bqv[8];
#pragma unroll
    for (int ct = 0; ct < 8; ++ct) {
        ksm[ct] = Ksum[s * 128 + ct * 16 + lr];
        bqv[ct] = b2f(bq[ct * 16 + lr]);
    }
    float zden[2][4];
#pragma unroll
    for (int mt = 0; mt < 2; ++mt)
#pragma unroll
        for (int j = 0; j < 4; ++j) zden[mt][j] = 0.f;
#pragma unroll
    for (int mt = 0; mt < 2; ++mt)
#pragma unroll
        for (int ct = 0; ct < 8; ++ct) {
            int d = ct * 16 + lr;
#pragma unroll
            for (int j = 0; j < 4; ++j) {
                float qv = fmaxf(qacc[mt][ct][j] + bqv[ct], 0.f) + 1e-6f;
                u16 qb16 = f2b(qv);
                zden[mt][j] += b2f(qb16) * ksm[ct];
                int b = w * 32 + mt * 16 + quad * 4 + j;
                Qs[sw16(b, d)] = qb16;
            }
        }
#pragma unroll
    for (int mt = 0; mt < 2; ++mt)
#pragma unroll
        for (int j = 0; j < 4; ++j) {
            float v = zden[mt][j];
            v += __shfl_xor(v, 1, 64); v += __shfl_xor(v, 2, 64);
            v += __shfl_xor(v, 4, 64); v += __shfl_xor(v, 8, 64);
            zden[mt][j] = 1.f / (v + 1e-6f);
        }
    // ---- O = Q · KV  (KVt B-frags direct from global) ----
    const u16* KVg = KVt + (size_t)s * (DM * DM);
    f32x4 oacc[2][8];
#pragma unroll
    for (int mt = 0; mt < 2; ++mt)
#pragma unroll
        for (int ct = 0; ct < 8; ++ct) oacc[mt][ct] = z4;
#pragma unroll
    for (int kc = 0; kc < 4; ++kc) {
        bf16x8 qa[2];
#pragma unroll
        for (int mt = 0; mt < 2; ++mt)
            qa[mt] = *(const bf16x8*)(Qs + sw16(w * 32 + mt * 16 + lr, kc * 32 + quad * 8));
#pragma unroll
        for (int ct = 0; ct < 8; ++ct) {
            bf16x8 kf = *(const bf16x8*)(KVg + (ct * 16 + lr) * DM + kc * 32 + quad * 8);
            oacc[0][ct] = __builtin_amdgcn_mfma_f32_16x16x32_bf16(qa[0], kf, oacc[0][ct], 0, 0, 0);
            oacc[1][ct] = __builtin_amdgcn_mfma_f32_16x16x32_bf16(qa[1], kf, oacc[1][ct], 0, 0, 0);
        }
    }
    float gv[8], bev[8];
#pragma unroll
    for (int ct = 0; ct < 8; ++ct) {
        gv[ct]  = b2f(g[ct * 16 + lr]);
        bev[ct] = b2f(beta[ct * 16 + lr]);
    }
#pragma unroll
    for (int mt = 0; mt < 2; ++mt)
#pragma unroll
        for (int j = 0; j < 4; ++j) {
            int b = w * 32 + mt * 16 + quad * 4 + j;
            const u16* xr = X + (m0 + b) * DM;
            float vals[8], sum = 0.f, sq = 0.f;
#pragma unroll
            for (int ct = 0; ct < 8; ++ct) {
                float v = fmaf(oacc[mt][ct][j], zden[mt][j], b2f(xr[ct * 16 + lr]));
                vals[ct] = v; sum += v; sq += v * v;
            }
            sum += __shfl_xor(sum, 1, 64); sq += __shfl_xor(sq, 1, 64);
            sum += __shfl_xor(sum, 2, 64); sq += __shfl_xor(sq, 2, 64);
            sum += __shfl_xor(sum, 4, 64); sq += __shfl_xor(sq, 4, 64);
            sum += __shfl_xor(sum, 8, 64); sq += __shfl_xor(sq, 8, 64);
            float mean = sum * 0.0078125f;
            float var  = sq * 0.0078125f - mean * mean;
            float rstd = rsqrtf(fmaxf(var, 0.f) + 1e-5f);
            u16* xo = Xout + (m0 + b) * DM;
#pragma unroll
            for (int ct = 0; ct < 8; ++ct)
                xo[ct * 16 + lr] = f2b((vals[ct] - mean) * rstd * gv[ct] + bev[ct]);
        }
}

// ================= fused MLP via MFMA, v3 =================
// Weight fragments direct global→VGPR (L1/L2-hot, wave-shared). LDS only for
// the H C→A transpose (16KB, wave-private rows) → kernel is BARRIER-FREE.
__global__ __launch_bounds__(256, 2) void mlp_kernel(
    const u16* X, const u16* __restrict__ W1, const u16* __restrict__ b1,
    const u16* __restrict__ W2, const u16* __restrict__ b2,
    u16* Xout, const u16* __restrict__ g, const u16* __restrict__ beta)
{
    __shared__ __align__(16) u16 Hc[128 * 64];    // [m][f_loc] 8-slot xor(m&7)
    const int t = threadIdx.x;
    const int m0 = blockIdx.x * 128;
    const int w = t >> 6, quad = (t >> 4) & 3, lr = t & 15;

    // X A/B-frags in registers: rows w*32+mt*16+lr, k = kc*32+quad*8
    bf16x8 xf[2][4];
#pragma unroll
    for (int mt = 0; mt < 2; ++mt)
#pragma unroll
        for (int kc = 0; kc < 4; ++kc)
            xf[mt][kc] = *(const bf16x8*)(X + (size_t)(m0 + w * 32 + mt * 16 + lr) * DM
                                            + kc * 32 + quad * 8);

    const f32x4 z4 = {0.f, 0.f, 0.f, 0.f};
    f32x4 zacc[2][8];
#pragma unroll
    for (int mt = 0; mt < 2; ++mt)
#pragma unroll
        for (int ct = 0; ct < 8; ++ct) zacc[mt][ct] = z4;

#pragma unroll 1
    for (int fc = 0; fc < DFF; fc += 64) {
        // ---- FF1 (transposed): D[f][m] = W1 · X^T, W1 frags direct global ----
        f32x4 hacc[2][4];
#pragma unroll
        for (int mt = 0; mt < 2; ++mt)
#pragma unroll
            for (int ct = 0; ct < 4; ++ct) hacc[mt][ct] = z4;
#pragma unroll
        for (int kc = 0; kc < 4; ++kc) {
#pragma unroll
            for (int ct = 0; ct < 4; ++ct) {
                bf16x8 wa = *(const bf16x8*)(W1 + (size_t)(fc + ct * 16 + lr) * DM
                                               + kc * 32 + quad * 8);
                hacc[0][ct] = __builtin_amdgcn_mfma_f32_16x16x32_bf16(wa, xf[0][kc], hacc[0][ct], 0, 0, 0);
                hacc[1][ct] = __builtin_amdgcn_mfma_f32_16x16x32_bf16(wa, xf[1][kc], hacc[1][ct], 0, 0, 0);
            }
        }
        // bias+relu; packed b64 store straight into FF2 A-frag layout (wave-private)
#pragma unroll
        for (int ct = 0; ct < 4; ++ct) {
            float hb[4];
#pragma unroll
            for (int j = 0; j < 4; ++j) hb[j] = b2f(b1[fc + ct * 16 + quad * 4 + j]);
#pragma unroll
            for (int mt = 0; mt < 2; ++mt) {
                int m = w * 32 + mt * 16 + lr;
                u16 h[4];
#pragma unroll
                for (int j = 0; j < 4; ++j)
                    h[j] = f2b(fmaxf(hacc[mt][ct][j] + hb[j], 0.f));
                uint2 pk; pk.x = (u32)h[0] | ((u32)h[1] << 16);
                pk.y = (u32)h[2] | ((u32)h[3] << 16);
                int slot = (ct * 2 + (quad >> 1)) ^ (m & 7);
                *(uint2*)(Hc + m * 64 + (slot << 3) + (quad & 1) * 4) = pk;
            }
        }
        // ---- FF2: zacc += H · W2^T, W2 frags direct global ----
#pragma unroll
        for (int kc = 0; kc < 2; ++kc) {
            bf16x8 ha[2];
#pragma unroll
            for (int mt = 0; mt < 2; ++mt) {
                int m = w * 32 + mt * 16 + lr;
                ha[mt] = *(const bf16x8*)(Hc + m * 64 + ((((kc * 4 + quad) ^ (m & 7)) & 7) << 3));
            }
#pragma unroll
            for (int ct = 0; ct < 8; ++ct) {
                bf16x8 wb = *(const bf16x8*)(W2 + (size_t)(ct * 16 + lr) * DFF + fc
                                               + kc * 32 + quad * 8);
                zacc[0][ct] = __builtin_amdgcn_mfma_f32_16x16x32_bf16(ha[0], wb, zacc[0][ct], 0, 0, 0);
                zacc[1][ct] = __builtin_amdgcn_mfma_f32_16x16x32_bf16(ha[1], wb, zacc[1][ct], 0, 0, 0);
            }
        }
    }
    // ---- epilogue: +b2, residual, register-only LN (r6-verified) ----
    float gv[8], bev[8], b2v[8];
#pragma unroll
    for (int ct = 0; ct < 8; ++ct) {
        gv[ct]  = b2f(g[ct * 16 + lr]);
        bev[ct] = b2f(beta[ct * 16 + lr]);
        b2v[ct] = b2f(b2[ct * 16 + lr]);
    }
#pragma unroll
    for (int mt = 0; mt < 2; ++mt)
#pragma unroll
        for (int j = 0; j < 4; ++j) {
            int r = w * 32 + mt * 16 + quad * 4 + j;
            const u16* xr = X + (size_t)(m0 + r) * DM;
            float vals[8], sum = 0.f, sq = 0.f;
#pragma unroll
            for (int ct = 0; ct < 8; ++ct) {
                float v = zacc[mt][ct][j] + b2v[ct] + b2f(xr[ct * 16 + lr]);
                vals[ct] = v; sum += v; sq += v * v;
            }
            sum += __shfl_xor(sum, 1, 64); sq += __shfl_xor(sq, 1, 64);
            sum += __shfl_xor(sum, 2, 64); sq += __shfl_xor(sq, 2, 64);
            sum += __shfl_xor(sum, 4, 64); sq += __shfl_xor(sq, 4, 64);
            sum += __shfl_xor(sum, 8, 64); sq += __shfl_xor(sq, 8, 64);
            float mean = sum * 0.0078125f;
            float var  = sq * 0.0078125f - mean * mean;
            float rstd = rsqrtf(fmaxf(var, 0.f) + 1e-5f);
            u16* xo = Xout + (size_t)(m0 + r) * DM;
#pragma unroll
            for (int ct = 0; ct < 8; ++ct)
                xo[ct * 16 + lr] = f2b((vals[ct] - mean) * rstd * gv[ct] + bev[ct]);
        }
}

// ================= mean over S + final FC =================
__global__ __launch_bounds__(128) void pool_fc_kernel(
    const u16* __restrict__ X, const u16* __restrict__ fcw,
    const u16* __restrict__ fcb, void* __restrict__ Out,
    const int* __restrict__ flag)
{
    __shared__ float pool[128];
    const int b = blockIdx.x, t = threadIdx.x;
    float acc = 0.f;
    for (int s = 0; s < S_LEN; ++s)
        acc += b2f(X[((size_t)s * B_SZ + b) * DM + t]);
    pool[t] = acc * (1.0f / 256.0f);
    __syncthreads();
    if (t < 10) {
        float o = b2f(fcb[t]);
        for (int d = 0; d < 128; ++d) o += pool[d] * b2f(fcw[t * 128 + d]);
        if (*flag) ((float*)Out)[b * 10 + t] = o;
        else       ((u16*)Out)[b * 10 + t] = f2b(o);
    }
}

// ================= launch =================
extern "C" void kernel_launch(void* const* d_in, const int* in_sizes, int n_in,
                              void* d_out, int out_size, void* d_ws, size_t ws_size,
                              hipStream_t stream)
{
    const int* src = (const int*)d_in[0];

    // ws: X bf16 33.5MB | KVt bf16 8.4MB | Ksum 128KB | flag | canon ~0.76MB
    char* ws = (char*)d_ws;
    u16*   X    = (u16*)ws;
    u16*   KVt  = (u16*)(ws + 33554432);
    float* Ksum = (float*)(ws + 41943040);
    int*   flag = (int*)(ws + 42074112);
    u16*   cn   = (u16*)(ws + 42074368);

    u16* emb = cn + 0;
    u16* wq  = cn + 16384;
    u16* bq  = cn + 49152;
    u16* wk  = cn + 49408;
    u16* bk  = cn + 82176;
    u16* wv  = cn + 82432;
    u16* bvp = cn + 115200;
    u16* w1  = cn + 115456;
    u16* b1  = cn + 246528;
    u16* w2  = cn + 247552;
    u16* b2  = cn + 378624;
    u16* g1  = cn + 378880;
    u16* be1 = cn + 379136;
    u16* g2  = cn + 379392;
    u16* be2 = cn + 379648;
    u16* fcw = cn + 379904;
    u16* fcb = cn + 381184;

    detect_kernel<<<1, 256, 0, stream>>>((const u32*)d_in[1], flag);

    Ptrs ps;
    for (int i = 0; i < 17; ++i) ps.p[i] = d_in[i + 1];
    convert_kernel<<<195, 256, 0, stream>>>(ps, cn, flag);

    embed_kernel<<<MROWS * 64 / 256, 256, 0, stream>>>(src, emb, X);

    for (int l = 0; l < 2; ++l) {
        kvproj_kernel<<<S_LEN, 256, 0, stream>>>(
            X, wk + l * DM * DM, bk + l * DM, wv + l * DM * DM, bvp + l * DM, KVt, Ksum);
        attn_ln_kernel<<<S_LEN * 4, 256, 0, stream>>>(
            X, wq + l * DM * DM, bq + l * DM, KVt, Ksum, X, g1 + l * DM, be1 + l * DM);
        mlp_kernel<<<MROWS / 128, 256, 0, stream>>>(
            X, w1 + l * DFF * DM, b1 + l * DFF, w2 + l * DM * DFF, b2 + l * DM,
            X, g2 + l * DM, be2 + l * DM);
    }

    pool_fc_kernel<<<B_SZ, 128, 0, stream>>>(X, fcw, fcb, d_out, flag);
}

// Round 8
// 463.914 us; speedup vs baseline: 1.4004x; 1.4004x over previous
//
#include <hip/hip_runtime.h>

typedef unsigned short u16;
typedef unsigned int u32;
typedef short bf16x8 __attribute__((ext_vector_type(8)));
typedef float f32x4 __attribute__((ext_vector_type(4)));

// ---------- bf16 helpers ----------
__device__ __forceinline__ float b2f(u16 v) { return __uint_as_float(((u32)v) << 16); }
__device__ __forceinline__ u16 f2b(float f) {   // round-to-nearest-even
    u32 x = __float_as_uint(f);
    return (u16)((x + 0x7fffu + ((x >> 16) & 1u)) >> 16);
}
__device__ __forceinline__ float lo16(u32 w) { return __uint_as_float(w << 16); }
__device__ __forceinline__ float hi16(u32 w) { return __uint_as_float(w & 0xffff0000u); }

#define S_LEN 256
#define B_SZ  512
#define DM    128
#define DFF   512
#define MROWS (S_LEN * B_SZ)   // 131072

// swizzled LDS address for a [row][128] bf16 tile, 16 slots of 8
__device__ __forceinline__ int sw16(int r, int d) {
    return r * 128 + ((((d >> 3) ^ (r & 15)) & 15) << 3) + (d & 7);
}

// ================= dtype detect =================
__global__ __launch_bounds__(256) void detect_kernel(const u32* __restrict__ embw,
                                                     int* __restrict__ flag) {
    int z = 0, big = 0;
    for (int i = threadIdx.x; i < 8192; i += 256) {
        u32 w = embw[i];
        u32 lo = w & 0xffffu;
        if (lo == 0u) z++;
        else if (((lo >> 7) & 0xffu) >= 0xC0u) big++;
    }
#pragma unroll
    for (int off = 32; off > 0; off >>= 1) {
        z   += __shfl_xor(z, off, 64);
        big += __shfl_xor(big, off, 64);
    }
    __shared__ int zz[4], bb[4];
    if ((threadIdx.x & 63) == 0) { zz[threadIdx.x >> 6] = z; bb[threadIdx.x >> 6] = big; }
    __syncthreads();
    if (threadIdx.x == 0) {
        int Z = zz[0] + zz[1] + zz[2] + zz[3];
        int Bc = bb[0] + bb[1] + bb[2] + bb[3];
        flag[0] = (Z > 4096 || Bc > 16) ? 1 : 0;   // 1 = fp32 storage
    }
}

// ================= convert all float inputs -> canonical bf16 =================
struct Ptrs { const void* p[17]; };

__global__ __launch_bounds__(256) void convert_kernel(Ptrs ps, u16* __restrict__ canon,
                                                      const int* __restrict__ flag) {
    const int cnt[17] = {16384,32768,256,32768,256,32768,256,131072,1024,131072,
                         256,256,256,256,256,1280,10};
    const int off[17] = {0,16384,49152,49408,82176,82432,115200,115456,246528,
                         247552,378624,378880,379136,379392,379648,379904,381184};
    const int bst[18] = {0,8,24,25,41,42,58,59,123,124,188,189,190,191,192,193,194,195};
    const int isf = *flag;
    const int blk = blockIdx.x;
    int idx = 0;
#pragma unroll
    for (int i = 0; i < 17; ++i) if (blk >= bst[i + 1]) idx = i + 1;
    const int local = blk - bst[idx];
    const int n = cnt[idx];
    const void* sp = ps.p[idx];
    u16* dp = canon + off[idx];
#pragma unroll
    for (int j = 0; j < 8; ++j) {
        int e = local * 2048 + j * 256 + threadIdx.x;
        if (e < n) {
            u16 v = isf ? f2b(((const float*)sp)[e]) : ((const u16*)sp)[e];
            dp[e] = v;
        }
    }
}

// ================= embed + positional encoding → X bf16 =================
__global__ __launch_bounds__(256) void embed_kernel(const int* __restrict__ src,
                                                    const u16* __restrict__ emb,
                                                    u16* __restrict__ X) {
    int idx = blockIdx.x * 256 + threadIdx.x;      // one per bf16 pair
    int d2 = idx & 63;
    int m = idx >> 6;              // s*512 + b
    int s = m >> 9;
    int b = m & 511;
    int tok = src[b * S_LEN + s];
    int d = d2 * 2;
    float e0 = b2f(emb[tok * DM + d])     * 11.3137084989847604f; // sqrt(128)
    float e1 = b2f(emb[tok * DM + d + 1]) * 11.3137084989847604f;
    float ang = (float)s * expf((float)d * -0.0719557841560639f); // -ln(10000)/128
    float v0 = e0 + sinf(ang);
    float v1 = e1 + cosf(ang);
    u32 w = (u32)f2b(v0) | ((u32)f2b(v1) << 16);
    *(u32*)(X + (size_t)m * DM + d) = w;
}

// ================= kvproj (MFMA, r5-verified): per-s K/V proj + KV^T + Ksum ====
__global__ __launch_bounds__(256) void kvproj_kernel(
    const u16* __restrict__ X, const u16* __restrict__ Wk, const u16* __restrict__ bk,
    const u16* __restrict__ Wv, const u16* __restrict__ bv,
    u16* __restrict__ KVt, float* __restrict__ Ksum)
{
    __shared__ __align__(16) char sm_[49152];
    u16* Xs = (u16*)sm_;             // 16KB: 64 rows x 128 k, sw16
    u16* Kt = (u16*)(sm_ + 16384);   // 16KB: 128 d x 64 b, 8-slot swizzle
    u16* Vt = (u16*)(sm_ + 32768);   // 16KB: 128 e x 64 b
    const int s = blockIdx.x, t = threadIdx.x;
    const int w = t >> 6, quad = (t >> 4) & 3, lr = t & 15;
    const u16* Xg = X + (size_t)s * B_SZ * DM;

    bf16x8 wkf[2][4], wvf[2][4];
    float kb[2], vb[2];
#pragma unroll
    for (int ct = 0; ct < 2; ++ct) {
        int e = w * 32 + ct * 16 + lr;
#pragma unroll
        for (int kc = 0; kc < 4; ++kc) {
            wkf[ct][kc] = *(const bf16x8*)(Wk + e * 128 + kc * 32 + quad * 8);
            wvf[ct][kc] = *(const bf16x8*)(Wv + e * 128 + kc * 32 + quad * 8);
        }
        kb[ct] = b2f(bk[e]);
        vb[ct] = b2f(bv[e]);
    }

    const f32x4 z4 = {0.f, 0.f, 0.f, 0.f};
    f32x4 kvacc[2][8];
#pragma unroll
    for (int dt = 0; dt < 2; ++dt)
#pragma unroll
        for (int ct = 0; ct < 8; ++ct) kvacc[dt][ct] = z4;
    float ks[2] = {0.f, 0.f};

    for (int b0 = 0; b0 < B_SZ; b0 += 64) {
        __syncthreads();
#pragma unroll
        for (int i = 0; i < 4; ++i) {
            int e8 = (i * 256 + t) * 8; int r = e8 >> 7, k0 = e8 & 127;
            *(uint4*)(Xs + sw16(r, k0)) = *(const uint4*)(Xg + (size_t)(b0 + r) * DM + k0);
        }
        __syncthreads();
        f32x4 pa[4][2];
#pragma unroll
        for (int mt = 0; mt < 4; ++mt) { pa[mt][0] = z4; pa[mt][1] = z4; }
#pragma unroll
        for (int kc = 0; kc < 4; ++kc) {
            bf16x8 a[4];
#pragma unroll
            for (int mt = 0; mt < 4; ++mt)
                a[mt] = *(const bf16x8*)(Xs + sw16(mt * 16 + lr, kc * 32 + quad * 8));
#pragma unroll
            for (int ct = 0; ct < 2; ++ct)
#pragma unroll
                for (int mt = 0; mt < 4; ++mt)
                    pa[mt][ct] = __builtin_amdgcn_mfma_f32_16x16x32_bf16(a[mt], wkf[ct][kc], pa[mt][ct], 0, 0, 0);
        }
#pragma unroll
        for (int ct = 0; ct < 2; ++ct) {
            int e = w * 32 + ct * 16 + lr, e7 = e & 7;
#pragma unroll
            for (int mt = 0; mt < 4; ++mt) {
                u16 h[4]; float ssum = 0.f;
#pragma unroll
                for (int j = 0; j < 4; ++j) {
                    float v = fmaxf(pa[mt][ct][j] + kb[ct], 0.f) + 1e-6f;
                    h[j] = f2b(v); ssum += b2f(h[j]);
                }
                ks[ct] += ssum;
                uint2 pk; pk.x = (u32)h[0] | ((u32)h[1] << 16); pk.y = (u32)h[2] | ((u32)h[3] << 16);
                int bs = mt * 2 + (quad >> 1);
                *(uint2*)(Kt + e * 64 + (((bs ^ e7) & 7) << 3) + (quad & 1) * 4) = pk;
            }
        }
#pragma unroll
        for (int mt = 0; mt < 4; ++mt) { pa[mt][0] = z4; pa[mt][1] = z4; }
#pragma unroll
        for (int kc = 0; kc < 4; ++kc) {
            bf16x8 a[4];
#pragma unroll
            for (int mt = 0; mt < 4; ++mt)
                a[mt] = *(const bf16x8*)(Xs + sw16(mt * 16 + lr, kc * 32 + quad * 8));
#pragma unroll
            for (int ct = 0; ct < 2; ++ct)
#pragma unroll
                for (int mt = 0; mt < 4; ++mt)
                    pa[mt][ct] = __builtin_amdgcn_mfma_f32_16x16x32_bf16(a[mt], wvf[ct][kc], pa[mt][ct], 0, 0, 0);
        }
#pragma unroll
        for (int ct = 0; ct < 2; ++ct) {
            int e = w * 32 + ct * 16 + lr, e7 = e & 7;
#pragma unroll
            for (int mt = 0; mt < 4; ++mt) {
                u16 h[4];
#pragma unroll
                for (int j = 0; j < 4; ++j) h[j] = f2b(pa[mt][ct][j] + vb[ct]);
                uint2 pk; pk.x = (u32)h[0] | ((u32)h[1] << 16); pk.y = (u32)h[2] | ((u32)h[3] << 16);
                int bs = mt * 2 + (quad >> 1);
                *(uint2*)(Vt + e * 64 + (((bs ^ e7) & 7) << 3) + (quad & 1) * 4) = pk;
            }
        }
        __syncthreads();
#pragma unroll
        for (int kc = 0; kc < 2; ++kc) {
            bf16x8 ka[2];
#pragma unroll
            for (int dt = 0; dt < 2; ++dt) {
                int d = (2 * w + dt) * 16 + lr;
                ka[dt] = *(const bf16x8*)(Kt + d * 64 + ((((kc * 4 + quad) ^ (d & 7)) & 7) << 3));
            }
#pragma unroll
            for (int ct = 0; ct < 8; ++ct) {
                int e = ct * 16 + lr;
                bf16x8 vf = *(const bf16x8*)(Vt + e * 64 + ((((kc * 4 + quad) ^ (e & 7)) & 7) << 3));
                kvacc[0][ct] = __builtin_amdgcn_mfma_f32_16x16x32_bf16(ka[0], vf, kvacc[0][ct], 0, 0, 0);
                kvacc[1][ct] = __builtin_amdgcn_mfma_f32_16x16x32_bf16(ka[1], vf, kvacc[1][ct], 0, 0, 0);
            }
        }
    }
#pragma unroll
    for (int ct = 0; ct < 2; ++ct) {
        float v = ks[ct];
        v += __shfl_xor(v, 16, 64);
        v += __shfl_xor(v, 32, 64);
        if (quad == 0) Ksum[s * 128 + w * 32 + ct * 16 + lr] = v;
    }
    u16* KVg = KVt + (size_t)s * (DM * DM);
#pragma unroll
    for (int dt = 0; dt < 2; ++dt) {
        int d0 = (2 * w + dt) * 16 + quad * 4;
#pragma unroll
        for (int ct = 0; ct < 8; ++ct) {
            int e = ct * 16 + lr;
            u16 h[4];
#pragma unroll
            for (int j = 0; j < 4; ++j) h[j] = f2b(kvacc[dt][ct][j]);
            uint2 pk; pk.x = (u32)h[0] | ((u32)h[1] << 16); pk.y = (u32)h[2] | ((u32)h[3] << 16);
            *(uint2*)(KVg + e * 128 + d0) = pk;
        }
    }
}

// ================= attn (MFMA, r5-verified): Q-proj + Q·KV·Z + residual + LN ===
__global__ __launch_bounds__(256) void attn_ln_kernel(
    const u16* X, const u16* __restrict__ Wq, const u16* __restrict__ bq,
    const u16* __restrict__ KVt, const float* __restrict__ Ksum,
    u16* Xout, const u16* __restrict__ g, const u16* __restrict__ beta)
{
    __shared__ __align__(16) char sm_[65536];
    u16* R1 = (u16*)sm_;            // Wq staged → Qs (A-frag layout)
    u16* R2 = (u16*)(sm_ + 32768);  // Xc staged → KVt staged
    const int blk = blockIdx.x, s = blk >> 2, rc = blk & 3, t = threadIdx.x;
    const int w = t >> 6, quad = (t >> 4) & 3, lr = t & 15;
    const size_t m0 = (size_t)s * B_SZ + rc * 128;

#pragma unroll
    for (int i = 0; i < 8; ++i) {
        int e8 = (i * 256 + t) * 8; int r = e8 >> 7, k0 = e8 & 127;
        *(uint4*)(R1 + sw16(r, k0)) = *(const uint4*)(Wq + e8);
        *(uint4*)(R2 + sw16(r, k0)) = *(const uint4*)(X + (m0 + r) * DM + k0);
    }
    __syncthreads();
    const f32x4 z4 = {0.f, 0.f, 0.f, 0.f};
    f32x4 qacc[2][8];
#pragma unroll
    for (int mt = 0; mt < 2; ++mt)
#pragma unroll
        for (int ct = 0; ct < 8; ++ct) qacc[mt][ct] = z4;
#pragma unroll
    for (int kc = 0; kc < 4; ++kc) {
        bf16x8 a[2];
#pragma unroll
        for (int mt = 0; mt < 2; ++mt)
            a[mt] = *(const bf16x8*)(R2 + sw16(w * 32 + mt * 16 + lr, kc * 32 + quad * 8));
#pragma unroll
        for (int ct = 0; ct < 8; ++ct) {
            bf16x8 wf = *(const bf16x8*)(R1 + sw16(ct * 16 + lr, kc * 32 + quad * 8));
            qacc[0][ct] = __builtin_amdgcn_mfma_f32_16x16x32_bf16(a[0], wf, qacc[0][ct], 0, 0, 0);
            qacc[1][ct] = __builtin_amdgcn_mfma_f32_16x16x32_bf16(a[1], wf, qacc[1][ct], 0, 0, 0);
        }
    }
    __syncthreads();
    float ksm[8], bqv[8];
#pragma unroll
    for (int ct = 0; ct < 8; ++ct) {
        ksm[ct] = Ksum[s * 128 + ct * 16 + lr];
        bqv[ct] = b2f(bq[ct * 16 + lr]);
    }
    float zden[2][4];
#pragma unroll
    for (int mt = 0; mt < 2; ++mt)
#pragma unroll
        for (int j = 0; j < 4; ++j) zden[mt][j] = 0.f;
#pragma unroll
    for (int mt = 0; mt < 2; ++mt)
#pragma unroll
        for (int ct = 0; ct < 8; ++ct) {
            int d = ct * 16 + lr;
#pragma unroll
            for (int j = 0; j < 4; ++j) {
                float qv = fmaxf(qacc[mt][ct][j] + bqv[ct], 0.f) + 1e-6f;
                u16 qb16 = f2b(qv);
                zden[mt][j] += b2f(qb16) * ksm[ct];
                int b = w * 32 + mt * 16 + quad * 4 + j;
                R1[sw16(b, d)] = qb16;     // Qs
            }
        }
#pragma unroll
    for (int mt = 0; mt < 2; ++mt)
#pragma unroll
        for (int j = 0; j < 4; ++j) {
            float v = zden[mt][j];
            v += __shfl_xor(v, 1, 64); v += __shfl_xor(v, 2, 64);
            v += __shfl_xor(v, 4, 64); v += __shfl_xor(v, 8, 64);
            zden[mt][j] = 1.f / (v + 1e-6f);
        }
    const u16* KVg = KVt + (size_t)s * (DM * DM);
#pragma unroll
    for (int i = 0; i < 8; ++i) {
        int e8 = (i * 256 + t) * 8; int r = e8 >> 7, k0 = e8 & 127;
        *(uint4*)(R2 + sw16(r, k0)) = *(const uint4*)(KVg + e8);
    }
    __syncthreads();
    f32x4 oacc[2][8];
#pragma unroll
    for (int mt = 0; mt < 2; ++mt)
#pragma unroll
        for (int ct = 0; ct < 8; ++ct) oacc[mt][ct] = z4;
#pragma unroll
    for (int kc = 0; kc < 4; ++kc) {
        bf16x8 qa[2];
#pragma unroll
        for (int mt = 0; mt < 2; ++mt)
            qa[mt] = *(const bf16x8*)(R1 + sw16(w * 32 + mt * 16 + lr, kc * 32 + quad * 8));
#pragma unroll
        for (int ct = 0; ct < 8; ++ct) {
            bf16x8 kf = *(const bf16x8*)(R2 + sw16(ct * 16 + lr, kc * 32 + quad * 8));
            oacc[0][ct] = __builtin_amdgcn_mfma_f32_16x16x32_bf16(qa[0], kf, oacc[0][ct], 0, 0, 0);
            oacc[1][ct] = __builtin_amdgcn_mfma_f32_16x16x32_bf16(qa[1], kf, oacc[1][ct], 0, 0, 0);
        }
    }
    float gv[8], bev[8];
#pragma unroll
    for (int ct = 0; ct < 8; ++ct) {
        gv[ct]  = b2f(g[ct * 16 + lr]);
        bev[ct] = b2f(beta[ct * 16 + lr]);
    }
#pragma unroll
    for (int mt = 0; mt < 2; ++mt)
#pragma unroll
        for (int j = 0; j < 4; ++j) {
            int b = w * 32 + mt * 16 + quad * 4 + j;
            const u16* xr = X + (m0 + b) * DM;
            float vals[8], sum = 0.f, sq = 0.f;
#pragma unroll
            for (int ct = 0; ct < 8; ++ct) {
                float v = fmaf(oacc[mt][ct][j], zden[mt][j], b2f(xr[ct * 16 + lr]));
                vals[ct] = v; sum += v; sq += v * v;
            }
            sum += __shfl_xor(sum, 1, 64); sq += __shfl_xor(sq, 1, 64);
            sum += __shfl_xor(sum, 2, 64); sq += __shfl_xor(sq, 2, 64);
            sum += __shfl_xor(sum, 4, 64); sq += __shfl_xor(sq, 4, 64);
            sum += __shfl_xor(sum, 8, 64); sq += __shfl_xor(sq, 8, 64);
            float mean = sum * 0.0078125f;
            float var  = sq * 0.0078125f - mean * mean;
            float rstd = rsqrtf(fmaxf(var, 0.f) + 1e-5f);
            u16* xo = Xout + (m0 + b) * DM;
#pragma unroll
            for (int ct = 0; ct < 8; ++ct)
                xo[ct * 16 + lr] = f2b((vals[ct] - mean) * rstd * gv[ct] + bev[ct]);
        }
}

// ================= fused MLP via MFMA, v4 =================
// LDS-staged weights (coalesced), X frags VGPR-resident (read once from staged
// As, then As overlaid by W1c/W2c). FF1 transposed → packed b64 H stores into
// FF2 A-frag layout (wave-private Hc, no barrier). 2 barriers/iter. Register
// LN + LDS-transposed coalesced output stores. 48KB LDS → 3 blk/CU.
__global__ __launch_bounds__(256, 3) void mlp_kernel(
    const u16* X, const u16* __restrict__ W1, const u16* __restrict__ b1,
    const u16* __restrict__ W2, const u16* __restrict__ b2,
    u16* Xout, const u16* __restrict__ g, const u16* __restrict__ beta)
{
    __shared__ __align__(16) char sm_[49152];
    u16* As  = (u16*)sm_;             // 32KB staging X [r][k] sw16 (dead after frag read)
    u16* W1c = (u16*)sm_;             // 16KB [f_loc][k] sw16 (overlays As)
    u16* W2c = (u16*)(sm_ + 16384);   // 16KB [d][f_loc] 8-slot (overlays As)
    u16* Hc  = (u16*)(sm_ + 32768);   // 16KB [m][f_loc] 8-slot, wave-private rows
    u16* Out = (u16*)sm_;             // 34.8KB [r][d] stride 136 (epilogue overlay)
    const int t = threadIdx.x;
    const int m0 = blockIdx.x * 128;
    const int w = t >> 6, quad = (t >> 4) & 3, lr = t & 15;

    // stage X tile coalesced, then pull frags to VGPRs
#pragma unroll
    for (int i = 0; i < 8; ++i) {
        int e8 = (i * 256 + t) * 8; int r = e8 >> 7, k0 = e8 & 127;
        *(uint4*)(As + sw16(r, k0)) = *(const uint4*)(X + (size_t)(m0 + r) * DM + k0);
    }
    __syncthreads();
    bf16x8 xf[2][4];
#pragma unroll
    for (int mt = 0; mt < 2; ++mt)
#pragma unroll
        for (int kc = 0; kc < 4; ++kc)
            xf[mt][kc] = *(const bf16x8*)(As + sw16(w * 32 + mt * 16 + lr, kc * 32 + quad * 8));

    const f32x4 z4 = {0.f, 0.f, 0.f, 0.f};
    f32x4 zacc[2][8];
#pragma unroll
    for (int mt = 0; mt < 2; ++mt)
#pragma unroll
        for (int ct = 0; ct < 8; ++ct) zacc[mt][ct] = z4;

    for (int fc = 0; fc < DFF; fc += 64) {
        __syncthreads();   // prev FF2 W2c reads done; iter0: As frag reads done
#pragma unroll
        for (int i = 0; i < 4; ++i) {   // stage W1c: 64 f-rows x 128 k, coalesced
            int e8 = (i * 256 + t) * 8; int r = e8 >> 7, k0 = e8 & 127;
            *(uint4*)(W1c + sw16(r, k0)) = *(const uint4*)(W1 + (size_t)(fc + r) * DM + k0);
        }
#pragma unroll
        for (int i = 0; i < 4; ++i) {   // stage W2c: 128 d x 64 f, coalesced
            int e8 = (i * 256 + t) * 8; int d = e8 >> 6, f0 = e8 & 63;
            *(uint4*)(W2c + d * 64 + ((((f0 >> 3) ^ (d & 7)) & 7) << 3)) =
                *(const uint4*)(W2 + (size_t)d * DFF + fc + f0);
        }
        __syncthreads();
        // ---- FF1 (transposed): D[f][m] = W1 · X^T ----
        f32x4 hacc[2][4];
#pragma unroll
        for (int mt = 0; mt < 2; ++mt)
#pragma unroll
            for (int ct = 0; ct < 4; ++ct) hacc[mt][ct] = z4;
#pragma unroll
        for (int kc = 0; kc < 4; ++kc) {
#pragma unroll
            for (int ct = 0; ct < 4; ++ct) {
                bf16x8 wa = *(const bf16x8*)(W1c + sw16(ct * 16 + lr, kc * 32 + quad * 8));
                hacc[0][ct] = __builtin_amdgcn_mfma_f32_16x16x32_bf16(wa, xf[0][kc], hacc[0][ct], 0, 0, 0);
                hacc[1][ct] = __builtin_amdgcn_mfma_f32_16x16x32_bf16(wa, xf[1][kc], hacc[1][ct], 0, 0, 0);
            }
        }
        // bias+relu; packed b64 store straight into FF2 A-frag layout (wave-private)
#pragma unroll
        for (int ct = 0; ct < 4; ++ct) {
            float hb[4];
#pragma unroll
            for (int j = 0; j < 4; ++j) hb[j] = b2f(b1[fc + ct * 16 + quad * 4 + j]);
#pragma unroll
            for (int mt = 0; mt < 2; ++mt) {
                int m = w * 32 + mt * 16 + lr;
                u16 h[4];
#pragma unroll
                for (int j = 0; j < 4; ++j)
                    h[j] = f2b(fmaxf(hacc[mt][ct][j] + hb[j], 0.f));
                uint2 pk; pk.x = (u32)h[0] | ((u32)h[1] << 16);
                pk.y = (u32)h[2] | ((u32)h[3] << 16);
                int slot = (ct * 2 + (quad >> 1)) ^ (m & 7);
                *(uint2*)(Hc + m * 64 + (slot << 3) + (quad & 1) * 4) = pk;
            }
        }
        // ---- FF2: zacc += H · W2^T (same-wave LDS RAW: no barrier) ----
#pragma unroll
        for (int kc = 0; kc < 2; ++kc) {
            bf16x8 ha[2];
#pragma unroll
            for (int mt = 0; mt < 2; ++mt) {
                int m = w * 32 + mt * 16 + lr;
                ha[mt] = *(const bf16x8*)(Hc + m * 64 + ((((kc * 4 + quad) ^ (m & 7)) & 7) << 3));
            }
#pragma unroll
            for (int ct = 0; ct < 8; ++ct) {
                int d = ct * 16 + lr;
                bf16x8 wb = *(const bf16x8*)(W2c + d * 64 + ((((kc * 4 + quad) ^ (d & 7)) & 7) << 3));
                zacc[0][ct] = __builtin_amdgcn_mfma_f32_16x16x32_bf16(ha[0], wb, zacc[0][ct], 0, 0, 0);
                zacc[1][ct] = __builtin_amdgcn_mfma_f32_16x16x32_bf16(ha[1], wb, zacc[1][ct], 0, 0, 0);
            }
        }
    }
    __syncthreads();   // all FF2 LDS reads done; Out overlays W1c/W2c/Hc-head
    // ---- epilogue: +b2, residual, register LN → Out LDS → coalesced stores ----
    float gv[8], bev[8], b2v[8];
#pragma unroll
    for (int ct = 0; ct < 8; ++ct) {
        gv[ct]  = b2f(g[ct * 16 + lr]);
        bev[ct] = b2f(beta[ct * 16 + lr]);
        b2v[ct] = b2f(b2[ct * 16 + lr]);
    }
#pragma unroll
    for (int mt = 0; mt < 2; ++mt)
#pragma unroll
        for (int j = 0; j < 4; ++j) {
            int r = w * 32 + mt * 16 + quad * 4 + j;
            const u16* xr = X + (size_t)(m0 + r) * DM;
            float vals[8], sum = 0.f, sq = 0.f;
#pragma unroll
            for (int ct = 0; ct < 8; ++ct) {
                float v = zacc[mt][ct][j] + b2v[ct] + b2f(xr[ct * 16 + lr]);
                vals[ct] = v; sum += v; sq += v * v;
            }
            sum += __shfl_xor(sum, 1, 64); sq += __shfl_xor(sq, 1, 64);
            sum += __shfl_xor(sum, 2, 64); sq += __shfl_xor(sq, 2, 64);
            sum += __shfl_xor(sum, 4, 64); sq += __shfl_xor(sq, 4, 64);
            sum += __shfl_xor(sum, 8, 64); sq += __shfl_xor(sq, 8, 64);
            float mean = sum * 0.0078125f;
            float var  = sq * 0.0078125f - mean * mean;
            float rstd = rsqrtf(fmaxf(var, 0.f) + 1e-5f);
#pragma unroll
            for (int ct = 0; ct < 8; ++ct)
                Out[r * 136 + ct * 16 + lr] = f2b((vals[ct] - mean) * rstd * gv[ct] + bev[ct]);
        }
    __syncthreads();
#pragma unroll
    for (int i = 0; i < 8; ++i) {   // coalesced copyout
        int e8 = (i * 256 + t) * 8; int r = e8 >> 7, k0 = e8 & 127;
        uint4 v = *(const uint4*)(Out + r * 136 + k0);
        *(uint4*)(Xout + (size_t)(m0 + r) * DM + k0) = v;
    }
}

// ================= mean over S + final FC =================
__global__ __launch_bounds__(128) void pool_fc_kernel(
    const u16* __restrict__ X, const u16* __restrict__ fcw,
    const u16* __restrict__ fcb, void* __restrict__ Out,
    const int* __restrict__ flag)
{
    __shared__ float pool[128];
    const int b = blockIdx.x, t = threadIdx.x;
    float acc = 0.f;
    for (int s = 0; s < S_LEN; ++s)
        acc += b2f(X[((size_t)s * B_SZ + b) * DM + t]);
    pool[t] = acc * (1.0f / 256.0f);
    __syncthreads();
    if (t < 10) {
        float o = b2f(fcb[t]);
        for (int d = 0; d < 128; ++d) o += pool[d] * b2f(fcw[t * 128 + d]);
        if (*flag) ((float*)Out)[b * 10 + t] = o;
        else       ((u16*)Out)[b * 10 + t] = f2b(o);
    }
}

// ================= launch =================
extern "C" void kernel_launch(void* const* d_in, const int* in_sizes, int n_in,
                              void* d_out, int out_size, void* d_ws, size_t ws_size,
                              hipStream_t stream)
{
    const int* src = (const int*)d_in[0];

    // ws: X bf16 33.5MB | KVt bf16 8.4MB | Ksum 128KB | flag | canon ~0.76MB
    char* ws = (char*)d_ws;
    u16*   X    = (u16*)ws;
    u16*   KVt  = (u16*)(ws + 33554432);
    float* Ksum = (float*)(ws + 41943040);
    int*   flag = (int*)(ws + 42074112);
    u16*   cn   = (u16*)(ws + 42074368);

    u16* emb = cn + 0;
    u16* wq  = cn + 16384;
    u16* bq  = cn + 49152;
    u16* wk  = cn + 49408;
    u16* bk  = cn + 82176;
    u16* wv  = cn + 82432;
    u16* bvp = cn + 115200;
    u16* w1  = cn + 115456;
    u16* b1  = cn + 246528;
    u16* w2  = cn + 247552;
    u16* b2  = cn + 378624;
    u16* g1  = cn + 378880;
    u16* be1 = cn + 379136;
    u16* g2  = cn + 379392;
    u16* be2 = cn + 379648;
    u16* fcw = cn + 379904;
    u16* fcb = cn + 381184;

    detect_kernel<<<1, 256, 0, stream>>>((const u32*)d_in[1], flag);

    Ptrs ps;
    for (int i = 0; i < 17; ++i) ps.p[i] = d_in[i + 1];
    convert_kernel<<<195, 256, 0, stream>>>(ps, cn, flag);

    embed_kernel<<<MROWS * 64 / 256, 256, 0, stream>>>(src, emb, X);

    for (int l = 0; l < 2; ++l) {
        kvproj_kernel<<<S_LEN, 256, 0, stream>>>(
            X, wk + l * DM * DM, bk + l * DM, wv + l * DM * DM, bvp + l * DM, KVt, Ksum);
        attn_ln_kernel<<<S_LEN * 4, 256, 0, stream>>>(
            X, wq + l * DM * DM, bq + l * DM, KVt, Ksum, X, g1 + l * DM, be1 + l * DM);
        mlp_kernel<<<MROWS / 128, 256, 0, stream>>>(
            X, w1 + l * DFF * DM, b1 + l * DFF, w2 + l * DM * DFF, b2 + l * DM,
            X, g2 + l * DM, be2 + l * DM);
    }

    pool_fc_kernel<<<B_SZ, 128, 0, stream>>>(X, fcw, fcb, d_out, flag);
}

// Round 9
// 450.398 us; speedup vs baseline: 1.4424x; 1.0300x over previous
//
#include <hip/hip_runtime.h>

typedef unsigned short u16;
typedef unsigned int u32;
typedef short bf16x8 __attribute__((ext_vector_type(8)));
typedef float f32x4 __attribute__((ext_vector_type(4)));

// ---------- bf16 helpers ----------
__device__ __forceinline__ float b2f(u16 v) { return __uint_as_float(((u32)v) << 16); }
__device__ __forceinline__ u16 f2b(float f) {   // round-to-nearest-even
    u32 x = __float_as_uint(f);
    return (u16)((x + 0x7fffu + ((x >> 16) & 1u)) >> 16);
}

#define S_LEN 256
#define B_SZ  512
#define DM    128
#define DFF   512
#define MROWS (S_LEN * B_SZ)   // 131072

// swizzled LDS address for a [row][128] bf16 tile, 16 slots of 8
__device__ __forceinline__ int sw16(int r, int d) {
    return r * 128 + ((((d >> 3) ^ (r & 15)) & 15) << 3) + (d & 7);
}

// ================= dtype detect =================
__global__ __launch_bounds__(256) void detect_kernel(const u32* __restrict__ embw,
                                                     int* __restrict__ flag) {
    int z = 0, big = 0;
    for (int i = threadIdx.x; i < 8192; i += 256) {
        u32 w = embw[i];
        u32 lo = w & 0xffffu;
        if (lo == 0u) z++;
        else if (((lo >> 7) & 0xffu) >= 0xC0u) big++;
    }
#pragma unroll
    for (int off = 32; off > 0; off >>= 1) {
        z   += __shfl_xor(z, off, 64);
        big += __shfl_xor(big, off, 64);
    }
    __shared__ int zz[4], bb[4];
    if ((threadIdx.x & 63) == 0) { zz[threadIdx.x >> 6] = z; bb[threadIdx.x >> 6] = big; }
    __syncthreads();
    if (threadIdx.x == 0) {
        int Z = zz[0] + zz[1] + zz[2] + zz[3];
        int Bc = bb[0] + bb[1] + bb[2] + bb[3];
        flag[0] = (Z > 4096 || Bc > 16) ? 1 : 0;   // 1 = fp32 storage
    }
}

// ================= convert all float inputs -> canonical bf16 =================
struct Ptrs { const void* p[17]; };

__global__ __launch_bounds__(256) void convert_kernel(Ptrs ps, u16* __restrict__ canon,
                                                      const int* __restrict__ flag) {
    const int cnt[17] = {16384,32768,256,32768,256,32768,256,131072,1024,131072,
                         256,256,256,256,256,1280,10};
    const int off[17] = {0,16384,49152,49408,82176,82432,115200,115456,246528,
                         247552,378624,378880,379136,379392,379648,379904,381184};
    const int bst[18] = {0,8,24,25,41,42,58,59,123,124,188,189,190,191,192,193,194,195};
    const int isf = *flag;
    const int blk = blockIdx.x;
    int idx = 0;
#pragma unroll
    for (int i = 0; i < 17; ++i) if (blk >= bst[i + 1]) idx = i + 1;
    const int local = blk - bst[idx];
    const int n = cnt[idx];
    const void* sp = ps.p[idx];
    u16* dp = canon + off[idx];
#pragma unroll
    for (int j = 0; j < 8; ++j) {
        int e = local * 2048 + j * 256 + threadIdx.x;
        if (e < n) {
            u16 v = isf ? f2b(((const float*)sp)[e]) : ((const u16*)sp)[e];
            dp[e] = v;
        }
    }
}

// ================= embed + positional encoding → X bf16 =================
__global__ __launch_bounds__(256) void embed_kernel(const int* __restrict__ src,
                                                    const u16* __restrict__ emb,
                                                    u16* __restrict__ X) {
    int idx = blockIdx.x * 256 + threadIdx.x;      // one per bf16 pair
    int d2 = idx & 63;
    int m = idx >> 6;              // s*512 + b
    int s = m >> 9;
    int b = m & 511;
    int tok = src[b * S_LEN + s];
    int d = d2 * 2;
    float e0 = b2f(emb[tok * DM + d])     * 11.3137084989847604f; // sqrt(128)
    float e1 = b2f(emb[tok * DM + d + 1]) * 11.3137084989847604f;
    float ang = (float)s * expf((float)d * -0.0719557841560639f); // -ln(10000)/128
    float v0 = e0 + sinf(ang);
    float v1 = e1 + cosf(ang);
    u32 w = (u32)f2b(v0) | ((u32)f2b(v1) << 16);
    *(u32*)(X + (size_t)m * DM + d) = w;
}

// ================= kvproj (MFMA, r5-verified): per-s K/V proj + KV^T + Ksum ====
__global__ __launch_bounds__(256) void kvproj_kernel(
    const u16* __restrict__ X, const u16* __restrict__ Wk, const u16* __restrict__ bk,
    const u16* __restrict__ Wv, const u16* __restrict__ bv,
    u16* __restrict__ KVt, float* __restrict__ Ksum)
{
    __shared__ __align__(16) char sm_[49152];
    u16* Xs = (u16*)sm_;             // 16KB: 64 rows x 128 k, sw16
    u16* Kt = (u16*)(sm_ + 16384);   // 16KB: 128 d x 64 b, 8-slot swizzle
    u16* Vt = (u16*)(sm_ + 32768);   // 16KB: 128 e x 64 b
    const int s = blockIdx.x, t = threadIdx.x;
    const int w = t >> 6, quad = (t >> 4) & 3, lr = t & 15;
    const u16* Xg = X + (size_t)s * B_SZ * DM;

    bf16x8 wkf[2][4], wvf[2][4];
    float kb[2], vb[2];
#pragma unroll
    for (int ct = 0; ct < 2; ++ct) {
        int e = w * 32 + ct * 16 + lr;
#pragma unroll
        for (int kc = 0; kc < 4; ++kc) {
            wkf[ct][kc] = *(const bf16x8*)(Wk + e * 128 + kc * 32 + quad * 8);
            wvf[ct][kc] = *(const bf16x8*)(Wv + e * 128 + kc * 32 + quad * 8);
        }
        kb[ct] = b2f(bk[e]);
        vb[ct] = b2f(bv[e]);
    }

    const f32x4 z4 = {0.f, 0.f, 0.f, 0.f};
    f32x4 kvacc[2][8];
#pragma unroll
    for (int dt = 0; dt < 2; ++dt)
#pragma unroll
        for (int ct = 0; ct < 8; ++ct) kvacc[dt][ct] = z4;
    float ks[2] = {0.f, 0.f};

    for (int b0 = 0; b0 < B_SZ; b0 += 64) {
        __syncthreads();
#pragma unroll
        for (int i = 0; i < 4; ++i) {
            int e8 = (i * 256 + t) * 8; int r = e8 >> 7, k0 = e8 & 127;
            *(uint4*)(Xs + sw16(r, k0)) = *(const uint4*)(Xg + (size_t)(b0 + r) * DM + k0);
        }
        __syncthreads();
        f32x4 pa[4][2];
#pragma unroll
        for (int mt = 0; mt < 4; ++mt) { pa[mt][0] = z4; pa[mt][1] = z4; }
#pragma unroll
        for (int kc = 0; kc < 4; ++kc) {
            bf16x8 a[4];
#pragma unroll
            for (int mt = 0; mt < 4; ++mt)
                a[mt] = *(const bf16x8*)(Xs + sw16(mt * 16 + lr, kc * 32 + quad * 8));
#pragma unroll
            for (int ct = 0; ct < 2; ++ct)
#pragma unroll
                for (int mt = 0; mt < 4; ++mt)
                    pa[mt][ct] = __builtin_amdgcn_mfma_f32_16x16x32_bf16(a[mt], wkf[ct][kc], pa[mt][ct], 0, 0, 0);
        }
#pragma unroll
        for (int ct = 0; ct < 2; ++ct) {
            int e = w * 32 + ct * 16 + lr, e7 = e & 7;
#pragma unroll
            for (int mt = 0; mt < 4; ++mt) {
                u16 h[4]; float ssum = 0.f;
#pragma unroll
                for (int j = 0; j < 4; ++j) {
                    float v = fmaxf(pa[mt][ct][j] + kb[ct], 0.f) + 1e-6f;
                    h[j] = f2b(v); ssum += b2f(h[j]);
                }
                ks[ct] += ssum;
                uint2 pk; pk.x = (u32)h[0] | ((u32)h[1] << 16); pk.y = (u32)h[2] | ((u32)h[3] << 16);
                int bs = mt * 2 + (quad >> 1);
                *(uint2*)(Kt + e * 64 + (((bs ^ e7) & 7) << 3) + (quad & 1) * 4) = pk;
            }
        }
#pragma unroll
        for (int mt = 0; mt < 4; ++mt) { pa[mt][0] = z4; pa[mt][1] = z4; }
#pragma unroll
        for (int kc = 0; kc < 4; ++kc) {
            bf16x8 a[4];
#pragma unroll
            for (int mt = 0; mt < 4; ++mt)
                a[mt] = *(const bf16x8*)(Xs + sw16(mt * 16 + lr, kc * 32 + quad * 8));
#pragma unroll
            for (int ct = 0; ct < 2; ++ct)
#pragma unroll
                for (int mt = 0; mt < 4; ++mt)
                    pa[mt][ct] = __builtin_amdgcn_mfma_f32_16x16x32_bf16(a[mt], wvf[ct][kc], pa[mt][ct], 0, 0, 0);
        }
#pragma unroll
        for (int ct = 0; ct < 2; ++ct) {
            int e = w * 32 + ct * 16 + lr, e7 = e & 7;
#pragma unroll
            for (int mt = 0; mt < 4; ++mt) {
                u16 h[4];
#pragma unroll
                for (int j = 0; j < 4; ++j) h[j] = f2b(pa[mt][ct][j] + vb[ct]);
                uint2 pk; pk.x = (u32)h[0] | ((u32)h[1] << 16); pk.y = (u32)h[2] | ((u32)h[3] << 16);
                int bs = mt * 2 + (quad >> 1);
                *(uint2*)(Vt + e * 64 + (((bs ^ e7) & 7) << 3) + (quad & 1) * 4) = pk;
            }
        }
        __syncthreads();
#pragma unroll
        for (int kc = 0; kc < 2; ++kc) {
            bf16x8 ka[2];
#pragma unroll
            for (int dt = 0; dt < 2; ++dt) {
                int d = (2 * w + dt) * 16 + lr;
                ka[dt] = *(const bf16x8*)(Kt + d * 64 + ((((kc * 4 + quad) ^ (d & 7)) & 7) << 3));
            }
#pragma unroll
            for (int ct = 0; ct < 8; ++ct) {
                int e = ct * 16 + lr;
                bf16x8 vf = *(const bf16x8*)(Vt + e * 64 + ((((kc * 4 + quad) ^ (e & 7)) & 7) << 3));
                kvacc[0][ct] = __builtin_amdgcn_mfma_f32_16x16x32_bf16(ka[0], vf, kvacc[0][ct], 0, 0, 0);
                kvacc[1][ct] = __builtin_amdgcn_mfma_f32_16x16x32_bf16(ka[1], vf, kvacc[1][ct], 0, 0, 0);
            }
        }
    }
#pragma unroll
    for (int ct = 0; ct < 2; ++ct) {
        float v = ks[ct];
        v += __shfl_xor(v, 16, 64);
        v += __shfl_xor(v, 32, 64);
        if (quad == 0) Ksum[s * 128 + w * 32 + ct * 16 + lr] = v;
    }
    u16* KVg = KVt + (size_t)s * (DM * DM);
#pragma unroll
    for (int dt = 0; dt < 2; ++dt) {
        int d0 = (2 * w + dt) * 16 + quad * 4;
#pragma unroll
        for (int ct = 0; ct < 8; ++ct) {
            int e = ct * 16 + lr;
            u16 h[4];
#pragma unroll
            for (int j = 0; j < 4; ++j) h[j] = f2b(kvacc[dt][ct][j]);
            uint2 pk; pk.x = (u32)h[0] | ((u32)h[1] << 16); pk.y = (u32)h[2] | ((u32)h[3] << 16);
            *(uint2*)(KVg + e * 128 + d0) = pk;
        }
    }
}

// ================= FUSED attn + mlp =================
// block = (s, 128-row chunk). attn half = r5-verified; mlp half = r8-verified.
// X' (post-attn LN) lives only in LDS (R2) — never written to global.
// LDS: R1 32K (Wq→Qs→W1c+W2c→Out) | R2 32K (X→KVt→X') | Hc 16K. 80KB → 2 blk/CU.
__global__ __launch_bounds__(256, 2) void attn_mlp_kernel(
    const u16* X, const u16* __restrict__ Wq, const u16* __restrict__ bq,
    const u16* __restrict__ KVt, const float* __restrict__ Ksum,
    const u16* __restrict__ W1, const u16* __restrict__ b1,
    const u16* __restrict__ W2, const u16* __restrict__ b2,
    u16* Xout,
    const u16* __restrict__ g1v_, const u16* __restrict__ be1_,
    const u16* __restrict__ g2v_, const u16* __restrict__ be2_)
{
    __shared__ __align__(16) char sm_[81920];
    u16* R1  = (u16*)sm_;              // 32KB
    u16* R2  = (u16*)(sm_ + 32768);    // 32KB
    u16* Hc  = (u16*)(sm_ + 65536);    // 16KB [m][f_loc] 8-slot, wave-private rows
    u16* W1c = R1;                     // 16KB [f_loc][k] sw16
    u16* W2c = R1 + 8192;              // 16KB [d][f_loc] 8-slot
    u16* Out = R1;                     // 32KB [r][d] stride 128 (final epilogue)
    const int blk = blockIdx.x, s = blk >> 2, rc = blk & 3, t = threadIdx.x;
    const int w = t >> 6, quad = (t >> 4) & 3, lr = t & 15;
    const size_t m0 = (size_t)s * B_SZ + rc * 128;

    // ---- stage Wq → R1, X → R2 ----
#pragma unroll
    for (int i = 0; i < 8; ++i) {
        int e8 = (i * 256 + t) * 8; int r = e8 >> 7, k0 = e8 & 127;
        *(uint4*)(R1 + sw16(r, k0)) = *(const uint4*)(Wq + e8);
        *(uint4*)(R2 + sw16(r, k0)) = *(const uint4*)(X + (m0 + r) * DM + k0);
    }
    __syncthreads();
    // ---- Q projection ----
    const f32x4 z4 = {0.f, 0.f, 0.f, 0.f};
    f32x4 qacc[2][8];
#pragma unroll
    for (int mt = 0; mt < 2; ++mt)
#pragma unroll
        for (int ct = 0; ct < 8; ++ct) qacc[mt][ct] = z4;
#pragma unroll
    for (int kc = 0; kc < 4; ++kc) {
        bf16x8 a[2];
#pragma unroll
        for (int mt = 0; mt < 2; ++mt)
            a[mt] = *(const bf16x8*)(R2 + sw16(w * 32 + mt * 16 + lr, kc * 32 + quad * 8));
#pragma unroll
        for (int ct = 0; ct < 8; ++ct) {
            bf16x8 wf = *(const bf16x8*)(R1 + sw16(ct * 16 + lr, kc * 32 + quad * 8));
            qacc[0][ct] = __builtin_amdgcn_mfma_f32_16x16x32_bf16(a[0], wf, qacc[0][ct], 0, 0, 0);
            qacc[1][ct] = __builtin_amdgcn_mfma_f32_16x16x32_bf16(a[1], wf, qacc[1][ct], 0, 0, 0);
        }
    }
    __syncthreads();   // all R1/R2 reads done; both may be overwritten
    // ---- Q epilogue: relu+eps, Z partials (rounded Q), Qs → R1 (wave rows) ----
    float ksm[8], bqv[8];
#pragma unroll
    for (int ct = 0; ct < 8; ++ct) {
        ksm[ct] = Ksum[s * 128 + ct * 16 + lr];
        bqv[ct] = b2f(bq[ct * 16 + lr]);
    }
    float zden[2][4];
#pragma unroll
    for (int mt = 0; mt < 2; ++mt)
#pragma unroll
        for (int j = 0; j < 4; ++j) zden[mt][j] = 0.f;
#pragma unroll
    for (int mt = 0; mt < 2; ++mt)
#pragma unroll
        for (int ct = 0; ct < 8; ++ct) {
            int d = ct * 16 + lr;
#pragma unroll
            for (int j = 0; j < 4; ++j) {
                float qv = fmaxf(qacc[mt][ct][j] + bqv[ct], 0.f) + 1e-6f;
                u16 qb16 = f2b(qv);
                zden[mt][j] += b2f(qb16) * ksm[ct];
                int b = w * 32 + mt * 16 + quad * 4 + j;
                R1[sw16(b, d)] = qb16;     // Qs
            }
        }
#pragma unroll
    for (int mt = 0; mt < 2; ++mt)
#pragma unroll
        for (int j = 0; j < 4; ++j) {
            float v = zden[mt][j];
            v += __shfl_xor(v, 1, 64); v += __shfl_xor(v, 2, 64);
            v += __shfl_xor(v, 4, 64); v += __shfl_xor(v, 8, 64);
            zden[mt][j] = 1.f / (v + 1e-6f);
        }
    // ---- stage KVt → R2 (X tile dead) ----
    const u16* KVg = KVt + (size_t)s * (DM * DM);
#pragma unroll
    for (int i = 0; i < 8; ++i) {
        int e8 = (i * 256 + t) * 8; int r = e8 >> 7, k0 = e8 & 127;
        *(uint4*)(R2 + sw16(r, k0)) = *(const uint4*)(KVg + e8);
    }
    __syncthreads();
    // ---- O = Q · KV ----
    f32x4 oacc[2][8];
#pragma unroll
    for (int mt = 0; mt < 2; ++mt)
#pragma unroll
        for (int ct = 0; ct < 8; ++ct) oacc[mt][ct] = z4;
#pragma unroll
    for (int kc = 0; kc < 4; ++kc) {
        bf16x8 qa[2];
#pragma unroll
        for (int mt = 0; mt < 2; ++mt)
            qa[mt] = *(const bf16x8*)(R1 + sw16(w * 32 + mt * 16 + lr, kc * 32 + quad * 8));
#pragma unroll
        for (int ct = 0; ct < 8; ++ct) {
            bf16x8 kf = *(const bf16x8*)(R2 + sw16(ct * 16 + lr, kc * 32 + quad * 8));
            oacc[0][ct] = __builtin_amdgcn_mfma_f32_16x16x32_bf16(qa[0], kf, oacc[0][ct], 0, 0, 0);
            oacc[1][ct] = __builtin_amdgcn_mfma_f32_16x16x32_bf16(qa[1], kf, oacc[1][ct], 0, 0, 0);
        }
    }
    __syncthreads();   // all R1/R2 reads done (Qs, KVt dead)
    // ---- attn epilogue: *Z + residual(global X) + LN → X' into R2 (wave rows) ----
    {
        float gv[8], bev[8];
#pragma unroll
        for (int ct = 0; ct < 8; ++ct) {
            gv[ct]  = b2f(g1v_[ct * 16 + lr]);
            bev[ct] = b2f(be1_[ct * 16 + lr]);
        }
#pragma unroll
        for (int mt = 0; mt < 2; ++mt)
#pragma unroll
            for (int j = 0; j < 4; ++j) {
                int b = w * 32 + mt * 16 + quad * 4 + j;
                const u16* xr = X + (m0 + b) * DM;
                float vals[8], sum = 0.f, sq = 0.f;
#pragma unroll
                for (int ct = 0; ct < 8; ++ct) {
                    float v = fmaf(oacc[mt][ct][j], zden[mt][j], b2f(xr[ct * 16 + lr]));
                    vals[ct] = v; sum += v; sq += v * v;
                }
                sum += __shfl_xor(sum, 1, 64); sq += __shfl_xor(sq, 1, 64);
                sum += __shfl_xor(sum, 2, 64); sq += __shfl_xor(sq, 2, 64);
                sum += __shfl_xor(sum, 4, 64); sq += __shfl_xor(sq, 4, 64);
                sum += __shfl_xor(sum, 8, 64); sq += __shfl_xor(sq, 8, 64);
                float mean = sum * 0.0078125f;
                float var  = sq * 0.0078125f - mean * mean;
                float rstd = rsqrtf(fmaxf(var, 0.f) + 1e-5f);
#pragma unroll
                for (int ct = 0; ct < 8; ++ct)
                    R2[sw16(b, ct * 16 + lr)] =
                        f2b((vals[ct] - mean) * rstd * gv[ct] + bev[ct]);
            }
    }
    // ---- X' frags → VGPRs (same-wave rows; DS ops in-order, no barrier) ----
    bf16x8 xf[2][4];
#pragma unroll
    for (int mt = 0; mt < 2; ++mt)
#pragma unroll
        for (int kc = 0; kc < 4; ++kc)
            xf[mt][kc] = *(const bf16x8*)(R2 + sw16(w * 32 + mt * 16 + lr, kc * 32 + quad * 8));

    // ---- MLP fc-loop (r8-v4 structure; W1c/W2c overlay R1) ----
    f32x4 zacc[2][8];
#pragma unroll
    for (int mt = 0; mt < 2; ++mt)
#pragma unroll
        for (int ct = 0; ct < 8; ++ct) zacc[mt][ct] = z4;

    for (int fc = 0; fc < DFF; fc += 64) {
        __syncthreads();   // prev FF2 W2c reads done (iter0: Qs reads done)
#pragma unroll
        for (int i = 0; i < 4; ++i) {   // stage W1c coalesced
            int e8 = (i * 256 + t) * 8; int r = e8 >> 7, k0 = e8 & 127;
            *(uint4*)(W1c + sw16(r, k0)) = *(const uint4*)(W1 + (size_t)(fc + r) * DM + k0);
        }
#pragma unroll
        for (int i = 0; i < 4; ++i) {   // stage W2c coalesced
            int e8 = (i * 256 + t) * 8; int d = e8 >> 6, f0 = e8 & 63;
            *(uint4*)(W2c + d * 64 + ((((f0 >> 3) ^ (d & 7)) & 7) << 3)) =
                *(const uint4*)(W2 + (size_t)d * DFF + fc + f0);
        }
        __syncthreads();
        // FF1 (transposed): D[f][m] = W1 · X'^T
        f32x4 hacc[2][4];
#pragma unroll
        for (int mt = 0; mt < 2; ++mt)
#pragma unroll
            for (int ct = 0; ct < 4; ++ct) hacc[mt][ct] = z4;
#pragma unroll
        for (int kc = 0; kc < 4; ++kc) {
#pragma unroll
            for (int ct = 0; ct < 4; ++ct) {
                bf16x8 wa = *(const bf16x8*)(W1c + sw16(ct * 16 + lr, kc * 32 + quad * 8));
                hacc[0][ct] = __builtin_amdgcn_mfma_f32_16x16x32_bf16(wa, xf[0][kc], hacc[0][ct], 0, 0, 0);
                hacc[1][ct] = __builtin_amdgcn_mfma_f32_16x16x32_bf16(wa, xf[1][kc], hacc[1][ct], 0, 0, 0);
            }
        }
        // bias+relu → packed b64 into FF2 A-frag layout (wave-private Hc)
#pragma unroll
        for (int ct = 0; ct < 4; ++ct) {
            float hb[4];
#pragma unroll
            for (int j = 0; j < 4; ++j) hb[j] = b2f(b1[fc + ct * 16 + quad * 4 + j]);
#pragma unroll
            for (int mt = 0; mt < 2; ++mt) {
                int m = w * 32 + mt * 16 + lr;
                u16 h[4];
#pragma unroll
                for (int j = 0; j < 4; ++j)
                    h[j] = f2b(fmaxf(hacc[mt][ct][j] + hb[j], 0.f));
                uint2 pk; pk.x = (u32)h[0] | ((u32)h[1] << 16);
                pk.y = (u32)h[2] | ((u32)h[3] << 16);
                int slot = (ct * 2 + (quad >> 1)) ^ (m & 7);
                *(uint2*)(Hc + m * 64 + (slot << 3) + (quad & 1) * 4) = pk;
            }
        }
        // FF2 (same-wave LDS RAW: no barrier)
#pragma unroll
        for (int kc = 0; kc < 2; ++kc) {
            bf16x8 ha[2];
#pragma unroll
            for (int mt = 0; mt < 2; ++mt) {
                int m = w * 32 + mt * 16 + lr;
                ha[mt] = *(const bf16x8*)(Hc + m * 64 + ((((kc * 4 + quad) ^ (m & 7)) & 7) << 3));
            }
#pragma unroll
            for (int ct = 0; ct < 8; ++ct) {
                int d = ct * 16 + lr;
                bf16x8 wb = *(const bf16x8*)(W2c + d * 64 + ((((kc * 4 + quad) ^ (d & 7)) & 7) << 3));
                zacc[0][ct] = __builtin_amdgcn_mfma_f32_16x16x32_bf16(ha[0], wb, zacc[0][ct], 0, 0, 0);
                zacc[1][ct] = __builtin_amdgcn_mfma_f32_16x16x32_bf16(ha[1], wb, zacc[1][ct], 0, 0, 0);
            }
        }
    }
    __syncthreads();   // FF2 reads done; Out overlays R1
    // ---- MLP epilogue: +b2 + residual(X' from R2) + LN → Out → coalesced ----
    {
        float gv[8], bev[8], b2v[8];
#pragma unroll
        for (int ct = 0; ct < 8; ++ct) {
            gv[ct]  = b2f(g2v_[ct * 16 + lr]);
            bev[ct] = b2f(be2_[ct * 16 + lr]);
            b2v[ct] = b2f(b2[ct * 16 + lr]);
        }
#pragma unroll
        for (int mt = 0; mt < 2; ++mt)
#pragma unroll
            for (int j = 0; j < 4; ++j) {
                int r = w * 32 + mt * 16 + quad * 4 + j;
                float vals[8], sum = 0.f, sq = 0.f;
#pragma unroll
                for (int ct = 0; ct < 8; ++ct) {
                    float v = zacc[mt][ct][j] + b2v[ct] + b2f(R2[sw16(r, ct * 16 + lr)]);
                    vals[ct] = v; sum += v; sq += v * v;
                }
                sum += __shfl_xor(sum, 1, 64); sq += __shfl_xor(sq, 1, 64);
                sum += __shfl_xor(sum, 2, 64); sq += __shfl_xor(sq, 2, 64);
                sum += __shfl_xor(sum, 4, 64); sq += __shfl_xor(sq, 4, 64);
                sum += __shfl_xor(sum, 8, 64); sq += __shfl_xor(sq, 8, 64);
                float mean = sum * 0.0078125f;
                float var  = sq * 0.0078125f - mean * mean;
                float rstd = rsqrtf(fmaxf(var, 0.f) + 1e-5f);
#pragma unroll
                for (int ct = 0; ct < 8; ++ct)
                    Out[r * 128 + ct * 16 + lr] =
                        f2b((vals[ct] - mean) * rstd * gv[ct] + bev[ct]);
            }
    }
    __syncthreads();
#pragma unroll
    for (int i = 0; i < 8; ++i) {   // coalesced copyout
        int e8 = (i * 256 + t) * 8; int r = e8 >> 7, k0 = e8 & 127;
        uint4 v = *(const uint4*)(Out + r * 128 + k0);
        *(uint4*)(Xout + (m0 + r) * DM + k0) = v;
    }
}

// ================= mean over S + final FC =================
__global__ __launch_bounds__(128) void pool_fc_kernel(
    const u16* __restrict__ X, const u16* __restrict__ fcw,
    const u16* __restrict__ fcb, void* __restrict__ Out,
    const int* __restrict__ flag)
{
    __shared__ float pool[128];
    const int b = blockIdx.x, t = threadIdx.x;
    float acc = 0.f;
    for (int s = 0; s < S_LEN; ++s)
        acc += b2f(X[((size_t)s * B_SZ + b) * DM + t]);
    pool[t] = acc * (1.0f / 256.0f);
    __syncthreads();
    if (t < 10) {
        float o = b2f(fcb[t]);
        for (int d = 0; d < 128; ++d) o += pool[d] * b2f(fcw[t * 128 + d]);
        if (*flag) ((float*)Out)[b * 10 + t] = o;
        else       ((u16*)Out)[b * 10 + t] = f2b(o);
    }
}

// ================= launch =================
extern "C" void kernel_launch(void* const* d_in, const int* in_sizes, int n_in,
                              void* d_out, int out_size, void* d_ws, size_t ws_size,
                              hipStream_t stream)
{
    const int* src = (const int*)d_in[0];

    // ws: X bf16 33.5MB | KVt bf16 8.4MB | Ksum 128KB | flag | canon ~0.76MB
    char* ws = (char*)d_ws;
    u16*   X    = (u16*)ws;
    u16*   KVt  = (u16*)(ws + 33554432);
    float* Ksum = (float*)(ws + 41943040);
    int*   flag = (int*)(ws + 42074112);
    u16*   cn   = (u16*)(ws + 42074368);

    u16* emb = cn + 0;
    u16* wq  = cn + 16384;
    u16* bq  = cn + 49152;
    u16* wk  = cn + 49408;
    u16* bk  = cn + 82176;
    u16* wv  = cn + 82432;
    u16* bvp = cn + 115200;
    u16* w1  = cn + 115456;
    u16* b1  = cn + 246528;
    u16* w2  = cn + 247552;
    u16* b2  = cn + 378624;
    u16* g1  = cn + 378880;
    u16* be1 = cn + 379136;
    u16* g2  = cn + 379392;
    u16* be2 = cn + 379648;
    u16* fcw = cn + 379904;
    u16* fcb = cn + 381184;

    detect_kernel<<<1, 256, 0, stream>>>((const u32*)d_in[1], flag);

    Ptrs ps;
    for (int i = 0; i < 17; ++i) ps.p[i] = d_in[i + 1];
    convert_kernel<<<195, 256, 0, stream>>>(ps, cn, flag);

    embed_kernel<<<MROWS * 64 / 256, 256, 0, stream>>>(src, emb, X);

    for (int l = 0; l < 2; ++l) {
        kvproj_kernel<<<S_LEN, 256, 0, stream>>>(
            X, wk + l * DM * DM, bk + l * DM, wv + l * DM * DM, bvp + l * DM, KVt, Ksum);
        attn_mlp_kernel<<<S_LEN * 4, 256, 0, stream>>>(
            X, wq + l * DM * DM, bq + l * DM, KVt, Ksum,
            w1 + l * DFF * DM, b1 + l * DFF, w2 + l * DM * DFF, b2 + l * DM,
            X, g1 + l * DM, be1 + l * DM, g2 + l * DM, be2 + l * DM);
    }

    pool_fc_kernel<<<B_SZ, 128, 0, stream>>>(X, fcw, fcb, d_out, flag);
}